// Round 4
// baseline (27.823 us; speedup 1.0000x reference)
//
#include <hip/hip_runtime.h>

// Aggregation: out[b,c,oh,ow] = sum_{i,j in 0..2} xpad[b,c,oh+i,ow+j] * w[b, c%16, i*3+j, oh*64+ow]
// B=8, C=256, H=W=OH=OW=64, WC=16, G=16, K=3, PAD=1, STRIDE=1, DIL=1.
//
// R4 design: one block = (b, wc, 8-row strip), ALL 16 groups -> weight read exactly once.
// LDS x-tile: 16 ch x 10 rows x 72 floats (4 zero-pad cols, 64 data, 4 zero-pad) = 46080 B
// -> 3 blocks/CU. Threads are 8-wide: all halo reads are aligned vector LDS reads, branchless.
// Thread map: tid = ch4(2b) | row(3b) | lane8(3b). Each thread: 4 channels x 1 row x 8 cols.

#define NB 8
#define NC 256
#define NH 64
#define NW 64
#define NWC 16
#define NG 16
#define LROW 72              // 4 pad + 64 data + 4 pad
#define LCHR 10              // rows per channel strip (8 + 2 halo)
#define LCH (LCHR * LROW)    // 720 floats per channel

__global__ __launch_bounds__(256, 3) void agg_kernel(const float* __restrict__ x,
                                                     const float* __restrict__ wt,
                                                     float* __restrict__ out) {
    __shared__ float lds[NG * LCH];   // 11520 floats = 46080 B

    const int tid   = threadIdx.x;
    const int l8    = tid & 7;         // 8 lanes across width (8 cols each)
    const int row   = (tid >> 3) & 7;  // 8 rows per strip
    const int ch4   = tid >> 6;        // which 4-channel group this wave handles
    const int bid   = blockIdx.x;
    const int strip = bid & 7;         // 8 strips of 8 rows
    const int wc    = (bid >> 3) & 15;
    const int b     = bid >> 7;

    const int oh  = strip * 8 + row;
    const int ow0 = l8 * 8;

    // ---- stage x: 16 ch x 10 rows x 16 float4 = 2560 float4, 10 per thread ----
    float4 sv[10];
    int    laddr[10];
    const int r0 = strip * 8 - 1;      // global row of LDS row 0
#pragma unroll
    for (int k = 0; k < 10; ++k) {
        const int f   = tid + k * 256;     // 0..2559
        const int ch  = f / 160;           // 160 float4 per channel
        const int rem = f - ch * 160;
        const int r   = rem >> 4;          // 0..9
        const int c4  = rem & 15;
        const int gr  = r0 + r;
        float4 v = make_float4(0.f, 0.f, 0.f, 0.f);
        if ((unsigned)gr < (unsigned)NH) {
            const int c = ch * NWC + wc;
            v = *reinterpret_cast<const float4*>(
                x + (((b * NC + c) * NH + gr) * NW) + c4 * 4);
        }
        sv[k]    = v;
        laddr[k] = (ch * LCHR + r) * LROW + 4 + c4 * 4;
    }

    // ---- weight: 9 taps x 8 cols for this thread's pixel strip (reused for 4 channels) ----
    float w[9][8];
    {
        const float* wp = wt + ((b * NWC + wc) * 9) * (NH * NW) + oh * NW + ow0;
#pragma unroll
        for (int idx = 0; idx < 9; ++idx) {
            float4 a = *reinterpret_cast<const float4*>(wp + idx * (NH * NW));
            float4 q = *reinterpret_cast<const float4*>(wp + idx * (NH * NW) + 4);
            w[idx][0] = a.x; w[idx][1] = a.y; w[idx][2] = a.z; w[idx][3] = a.w;
            w[idx][4] = q.x; w[idx][5] = q.y; w[idx][6] = q.z; w[idx][7] = q.w;
        }
    }

    // ---- write staged data to LDS; zero the pad columns ----
#pragma unroll
    for (int k = 0; k < 10; ++k) {
        *reinterpret_cast<float4*>(&lds[laddr[k]]) = sv[k];
    }
    if (tid < NG * LCHR) {             // 160 rows: zero cols 0..3 and 68..71
        const float4 z = make_float4(0.f, 0.f, 0.f, 0.f);
        *reinterpret_cast<float4*>(&lds[tid * LROW])      = z;
        *reinterpret_cast<float4*>(&lds[tid * LROW + 68]) = z;
    }

    __syncthreads();

    // ---- compute: 4 channels per thread, 8 outputs each ----
#pragma unroll
    for (int cc = 0; cc < 4; ++cc) {
        const int g = ch4 * 4 + cc;
        const float* pch = &lds[g * LCH];
        float acc[8] = {0.f, 0.f, 0.f, 0.f, 0.f, 0.f, 0.f, 0.f};

#pragma unroll
        for (int i = 0; i < 3; ++i) {
            // output row oh uses global rows oh-1+i -> LDS row (row + i); data col c at lds col c+4
            const float* p = pch + (row + i) * LROW;
            float2 lo = *reinterpret_cast<const float2*>(p + ow0 + 2);   // data[ow0-2], data[ow0-1]
            float4 m0 = *reinterpret_cast<const float4*>(p + ow0 + 4);   // data[ow0..ow0+3]
            float4 m1 = *reinterpret_cast<const float4*>(p + ow0 + 8);   // data[ow0+4..ow0+7]
            float2 hi = *reinterpret_cast<const float2*>(p + ow0 + 12);  // data[ow0+8], data[ow0+9]
            float e[10];
            e[0] = lo.y;
            e[1] = m0.x; e[2] = m0.y; e[3] = m0.z; e[4] = m0.w;
            e[5] = m1.x; e[6] = m1.y; e[7] = m1.z; e[8] = m1.w;
            e[9] = hi.x;
#pragma unroll
            for (int j = 0; j < 3; ++j) {
#pragma unroll
                for (int t = 0; t < 8; ++t) {
                    acc[t] += e[t + j] * w[i * 3 + j][t];
                }
            }
        }

        float* op = out + (((b * NC + g * NWC + wc) * NH + oh) * NW) + ow0;
        *reinterpret_cast<float4*>(op)     = make_float4(acc[0], acc[1], acc[2], acc[3]);
        *reinterpret_cast<float4*>(op + 4) = make_float4(acc[4], acc[5], acc[6], acc[7]);
    }
}

extern "C" void kernel_launch(void* const* d_in, const int* in_sizes, int n_in,
                              void* d_out, int out_size, void* d_ws, size_t ws_size,
                              hipStream_t stream) {
    const float* x  = (const float*)d_in[0];
    const float* wt = (const float*)d_in[1];
    float* out      = (float*)d_out;

    // Grid: 8 b * 16 wc * 8 strips = 1024 blocks of 256 threads.
    dim3 grid(NB * NWC * 8);
    dim3 block(256);
    agg_kernel<<<grid, block, 0, stream>>>(x, wt, out);
}

// Round 5
// 25.070 us; speedup vs baseline: 1.1098x; 1.1098x over previous
//
#include <hip/hip_runtime.h>

// Aggregation: out[b,c,oh,ow] = sum_{i,j in 0..2} xpad[b,c,oh+i,ow+j] * w[b, c%16, i*3+j, oh*64+ow]
// B=8, C=256, H=W=OH=OW=64, WC=16, G=16, K=3, PAD=1, STRIDE=1, DIL=1.
//
// R5: block = (b, wc, 16-row strip); ALL 16 groups per block -> weight read exactly once.
// Thread map (R3-proven): tid = row(4b) | lane16(4b); each thread: 1 row x 4 cols x 16 ch.
// All wave-level global accesses are 1 KB contiguous. LDS rows have a 4-float zeroed right
// pad which doubles as the LEFT halo of the following row (col -4 read of row r lands in
// row r-1's zeroed pad); a 4-float guard covers the first row. All halo reads are aligned
// ds_read_b128 - zero scalar LDS reads, branchless.
// LDS = 4 + 16ch*18rows*68 floats = 78352 B -> exactly 2 blocks/CU; grid 512 = 2/CU, no tail.

#define NB 8
#define NC 256
#define NH 64
#define NW 64
#define NWC 16
#define NG 16
#define LROW 68              // 64 data + 4 zeroed pad (pad = left halo of next row)
#define LCH (18 * LROW)      // 1224 floats per channel strip

__global__ __launch_bounds__(256, 2) void agg_kernel(const float* __restrict__ x,
                                                     const float* __restrict__ wt,
                                                     float* __restrict__ out) {
    __shared__ float lds[4 + NG * LCH];   // 19588 floats = 78352 B

    const int tid   = threadIdx.x;
    const int l16   = tid & 15;
    const int row   = tid >> 4;        // 0..15
    const int bid   = blockIdx.x;
    const int strip = bid & 3;         // 4 strips of 16 rows
    const int wc    = (bid >> 2) & 15;
    const int b     = bid >> 6;

    const int oh  = strip * 16 + row;
    const int ow0 = l16 * 4;
    const int r0  = strip * 16;        // global row of LDS row 1

    // ---- stage main 16 rows: 16ch x 16r x 16 float4 = 4096 f4, 16/thread (pow2 map) ----
#pragma unroll
    for (int k = 0; k < 16; ++k) {
        const int f   = tid + k * 256;
        const int ch  = f >> 8;
        const int rem = f & 255;
        const int r   = rem >> 4;      // 0..15
        const int c4  = rem & 15;
        const int c   = ch * NWC + wc;
        float4 v = *reinterpret_cast<const float4*>(
            x + (((b * NC + c) * NH + (r0 + r)) * NW) + c4 * 4);
        *reinterpret_cast<float4*>(&lds[4 + ch * LCH + (r + 1) * LROW + c4 * 4]) = v;
    }

    // ---- stage 2 halo rows: 16ch x 16 f4 each ----
    {
        const int ch = tid >> 4;
        const int c4 = tid & 15;
        const int c  = ch * NWC + wc;
        const float* xc = x + ((b * NC + c) * NH) * NW + c4 * 4;
        float4 vt = make_float4(0.f, 0.f, 0.f, 0.f);
        float4 vb = make_float4(0.f, 0.f, 0.f, 0.f);
        if (r0 - 1 >= 0)  vt = *reinterpret_cast<const float4*>(xc + (r0 - 1) * NW);
        if (r0 + 16 < NH) vb = *reinterpret_cast<const float4*>(xc + (r0 + 16) * NW);
        *reinterpret_cast<float4*>(&lds[4 + ch * LCH + 0 * LROW + c4 * 4])  = vt;
        *reinterpret_cast<float4*>(&lds[4 + ch * LCH + 17 * LROW + c4 * 4]) = vb;
    }

    // ---- zero the pads: 288 row-pads (4 floats each) + 4-float guard ----
    {
        const float4 z = make_float4(0.f, 0.f, 0.f, 0.f);
        if (tid == 0) *reinterpret_cast<float4*>(&lds[0]) = z;
        *reinterpret_cast<float4*>(&lds[4 + tid * LROW + 64]) = z;
        if (tid < 32) *reinterpret_cast<float4*>(&lds[4 + (tid + 256) * LROW + 64]) = z;
    }

    // ---- weights: 9 taps x 4 cols for this pixel-quad (reused for all 16 channels) ----
    float w[9][4];
    {
        const float* wp = wt + ((b * NWC + wc) * 9) * (NH * NW) + oh * NW + ow0;
#pragma unroll
        for (int idx = 0; idx < 9; ++idx) {
            float4 t = *reinterpret_cast<const float4*>(wp + idx * (NH * NW));
            w[idx][0] = t.x; w[idx][1] = t.y; w[idx][2] = t.z; w[idx][3] = t.w;
        }
    }

    __syncthreads();

    // ---- compute: 16 channels x 4 outputs per thread; halos via aligned b128 only ----
#pragma unroll
    for (int ch = 0; ch < NG; ++ch) {
        const float* pch = &lds[4 + ch * LCH];
        float acc[4] = {0.f, 0.f, 0.f, 0.f};

#pragma unroll
        for (int i = 0; i < 3; ++i) {
            // output row oh (LDS row row+1) tap i reads LDS row (row + i)
            const float* p = pch + (row + i) * LROW + ow0;
            float4 v0 = *reinterpret_cast<const float4*>(p - 4);  // cols ow0-4..ow0-1 (pad/guard when l16==0)
            float4 v1 = *reinterpret_cast<const float4*>(p);      // cols ow0..ow0+3
            float4 v2 = *reinterpret_cast<const float4*>(p + 4);  // cols ow0+4..ow0+7 (pad when l16==15)
            const float e0 = v0.w;
            const float e5 = v2.x;
#pragma unroll
            for (int j = 0; j < 3; ++j) {
                const float* wj = w[i * 3 + j];
                const float e[6] = {e0, v1.x, v1.y, v1.z, v1.w, e5};
                acc[0] += e[0 + j] * wj[0];
                acc[1] += e[1 + j] * wj[1];
                acc[2] += e[2 + j] * wj[2];
                acc[3] += e[3 + j] * wj[3];
            }
        }

        float* op = out + (((b * NC + ch * NWC + wc) * NH + oh) * NW) + ow0;
        *reinterpret_cast<float4*>(op) = make_float4(acc[0], acc[1], acc[2], acc[3]);
    }
}

extern "C" void kernel_launch(void* const* d_in, const int* in_sizes, int n_in,
                              void* d_out, int out_size, void* d_ws, size_t ws_size,
                              hipStream_t stream) {
    const float* x  = (const float*)d_in[0];
    const float* wt = (const float*)d_in[1];
    float* out      = (float*)d_out;

    // Grid: 8 b * 16 wc * 4 strips = 512 blocks of 256 threads = exactly 2 blocks/CU.
    dim3 grid(NB * NWC * 4);
    dim3 block(256);
    agg_kernel<<<grid, block, 0, stream>>>(x, wt, out);
}

// Round 6
// 21.391 us; speedup vs baseline: 1.3007x; 1.1720x over previous
//
#include <hip/hip_runtime.h>

// Aggregation: out[b,c,oh,ow] = sum_{i,j in 0..2} xpad[b,c,oh+i,ow+j] * w[b, c%16, i*3+j, oh*64+ow]
// B=8, C=256, H=W=OH=OW=64, WC=16, G=16, K=3, PAD=1, STRIDE=1, DIL=1.
//
// R6: CPB=16 (weight read ONCE) at R3's proven occupancy point (16 waves/CU, one round).
// Block = (b, wc, 8-row strip); LDS = 16ch x 10rows x 64 floats = 40960 B EXACTLY
// -> 4 blocks/CU (163840 B), grid 1024 = exactly 4/CU, no tail.
// Thread map: tid = h(1b) | row(3b) | l16(4b). Each thread: 8 channels x 1 row x 4 cols.
// LDS reads per (ch,i): 1 ds_read_b128 + 2 b32 halos (2-way bank alias = free) + cndmask.
// OOB LDS reads (ch0/row0 col -1, ch15/row9 col +4) return 0 in HW and are masked anyway.
// All wave-level global accesses (stage, weights, stores) are 1 KB contiguous.

#define NB 8
#define NC 256
#define NH 64
#define NW 64
#define NWC 16
#define NG 16
#define STRIP 8
#define LCHR 10              // 8 rows + 2 halo
#define LROW 64
#define LCH (LCHR * LROW)    // 640 floats per channel

__global__ __launch_bounds__(256, 4) void agg_kernel(const float* __restrict__ x,
                                                     const float* __restrict__ wt,
                                                     float* __restrict__ out) {
    __shared__ float lds[NG * LCH];   // 10240 floats = 40960 B exactly

    const int tid   = threadIdx.x;
    const int l16   = tid & 15;
    const int row   = (tid >> 4) & 7;  // 0..7 within strip
    const int h     = tid >> 7;        // 0/1: which 8-channel half this thread computes
    const int bid   = blockIdx.x;
    const int strip = bid & 7;         // 8 strips of 8 rows
    const int wc    = (bid >> 3) & 15;
    const int b     = bid >> 7;

    const int oh  = strip * STRIP + row;
    const int ow0 = l16 * 4;
    const int r0  = strip * STRIP - 1;   // global row of LDS row 0

    // ---- issue ALL stage loads first (MLP): 16ch x 10r x 16 f4 = 2560 f4, 10/thread ----
    float4 sv[10];
    int    laddr[10];
#pragma unroll
    for (int k = 0; k < 10; ++k) {
        const int f   = tid + k * 256;   // 0..2559
        const int ch  = f / 160;         // 160 f4 per channel
        const int rem = f - ch * 160;
        const int r   = rem >> 4;        // 0..9
        const int c4  = rem & 15;
        const int gr  = r0 + r;
        float4 v = make_float4(0.f, 0.f, 0.f, 0.f);
        if ((unsigned)gr < (unsigned)NH) {
            const int c = ch * NWC + wc;
            v = *reinterpret_cast<const float4*>(
                x + (((b * NC + c) * NH + gr) * NW) + c4 * 4);
        }
        sv[k]    = v;
        laddr[k] = ch * LCH + r * LROW + c4 * 4;
    }

    // ---- weights: 9 taps x 4 cols for this pixel-quad (reused for 8 channels) ----
    float w[9][4];
    {
        const float* wp = wt + ((b * NWC + wc) * 9) * (NH * NW) + oh * NW + ow0;
#pragma unroll
        for (int idx = 0; idx < 9; ++idx) {
            float4 t = *reinterpret_cast<const float4*>(wp + idx * (NH * NW));
            w[idx][0] = t.x; w[idx][1] = t.y; w[idx][2] = t.z; w[idx][3] = t.w;
        }
    }

    // ---- LDS writes ----
#pragma unroll
    for (int k = 0; k < 10; ++k) {
        *reinterpret_cast<float4*>(&lds[laddr[k]]) = sv[k];
    }

    __syncthreads();

    const bool has_left  = (l16 > 0);
    const bool has_right = (l16 < 15);

    // ---- compute: 8 channels x 4 outputs per thread ----
#pragma unroll
    for (int cc = 0; cc < 8; ++cc) {
        const int ch = h * 8 + cc;
        const float* pch = &lds[ch * LCH];
        float acc[4] = {0.f, 0.f, 0.f, 0.f};

#pragma unroll
        for (int i = 0; i < 3; ++i) {
            // output row `row` tap i -> LDS row (row + i), 0..9
            const float* p = pch + (row + i) * LROW + ow0;
            float4 m = *reinterpret_cast<const float4*>(p);
            const float e0 = has_left  ? p[-1] : 0.f;   // OOB/garbage masked
            const float e5 = has_right ? p[4]  : 0.f;
            const float e[6] = {e0, m.x, m.y, m.z, m.w, e5};
#pragma unroll
            for (int j = 0; j < 3; ++j) {
                const float* wj = w[i * 3 + j];
                acc[0] += e[0 + j] * wj[0];
                acc[1] += e[1 + j] * wj[1];
                acc[2] += e[2 + j] * wj[2];
                acc[3] += e[3 + j] * wj[3];
            }
        }

        float* op = out + (((b * NC + ch * NWC + wc) * NH + oh) * NW) + ow0;
        *reinterpret_cast<float4*>(op) = make_float4(acc[0], acc[1], acc[2], acc[3]);
    }
}

extern "C" void kernel_launch(void* const* d_in, const int* in_sizes, int n_in,
                              void* d_out, int out_size, void* d_ws, size_t ws_size,
                              hipStream_t stream) {
    const float* x  = (const float*)d_in[0];
    const float* wt = (const float*)d_in[1];
    float* out      = (float*)d_out;

    // Grid: 8 b * 16 wc * 8 strips = 1024 blocks of 256 threads = exactly 4 blocks/CU.
    dim3 grid(NB * NWC * 8);
    dim3 block(256);
    agg_kernel<<<grid, block, 0, stream>>>(x, wt, out);
}